// Round 7
// baseline (677.358 us; speedup 1.0000x reference)
//
#include <hip/hip_runtime.h>

#define FD 128      // feature dim (D == H == 128)
#define SCAN_B 256  // blocks in hierarchical scan
#define SCAN_T 256  // threads per scan block

// ---------------- degree ----------------

__global__ void k_deg(const int* __restrict__ dst, int* __restrict__ deg, int E) {
  int e = blockIdx.x * blockDim.x + threadIdx.x;
  if (e < E) atomicAdd(&deg[dst[e]], 1);
}

// ---------------- hierarchical scan: partials (+ fused dinv) ----------------

__global__ __launch_bounds__(SCAN_T) void k_part(const int* __restrict__ deg,
                                                 float* __restrict__ dinv,
                                                 int* __restrict__ part, int n) {
  const int b = blockIdx.x;
  const int chunk = (n + SCAN_B - 1) / SCAN_B;
  const int lo = b * chunk;
  const int hi = min(lo + chunk, n);
  int sum = 0;
  for (int i = lo + threadIdx.x; i < hi; i += SCAN_T) {
    int d = deg[i];
    sum += d;
    dinv[i] = rsqrtf((float)(d + 1));   // +1 = self-loop
  }
  __shared__ int red[SCAN_T / 64];
  for (int off = 32; off > 0; off >>= 1) sum += __shfl_down(sum, off, 64);
  if ((threadIdx.x & 63) == 0) red[threadIdx.x >> 6] = sum;
  __syncthreads();
  if (threadIdx.x == 0) {
    int s = 0;
#pragma unroll
    for (int w = 0; w < SCAN_T / 64; ++w) s += red[w];
    part[b] = s;
  }
}

__global__ __launch_bounds__(SCAN_B) void k_scanpart(int* __restrict__ part,
                                                     int* __restrict__ row_ptr, int n) {
  __shared__ int s[SCAN_B];
  const int t = threadIdx.x;
  int v = part[t];
  s[t] = v;
  __syncthreads();
  for (int off = 1; off < SCAN_B; off <<= 1) {
    int u = (t >= off) ? s[t - off] : 0;
    __syncthreads();
    s[t] += u;
    __syncthreads();
  }
  part[t] = s[t] - v;                    // exclusive
  if (t == SCAN_B - 1) row_ptr[n] = s[t];
}

__global__ __launch_bounds__(SCAN_T) void k_rowptr(const int* __restrict__ deg,
                                                   const int* __restrict__ part,
                                                   int* __restrict__ row_ptr,
                                                   int* __restrict__ cursor, int n) {
  const int b = blockIdx.x;
  const int chunk = (n + SCAN_B - 1) / SCAN_B;
  const int lo = b * chunk;
  const int hi = min(lo + chunk, n);
  const int sub = (chunk + SCAN_T - 1) / SCAN_T;
  const int t = threadIdx.x;
  const int slo = min(lo + t * sub, hi);
  const int shi = min(slo + sub, hi);
  int sum = 0;
  for (int i = slo; i < shi; ++i) sum += deg[i];
  __shared__ int s[SCAN_T];
  s[t] = sum;
  __syncthreads();
  for (int off = 1; off < SCAN_T; off <<= 1) {
    int u = (t >= off) ? s[t - off] : 0;
    __syncthreads();
    s[t] += u;
    __syncthreads();
  }
  int run = part[b] + s[t] - sum;
  for (int i = slo; i < shi; ++i) {
    row_ptr[i] = run;
    cursor[i]  = run;
    run += deg[i];
  }
}

// ---------------- CSR fill: src index only (coef recomputed in agg) ----------------

__global__ void k_fill(const int* __restrict__ src, const int* __restrict__ dst,
                       int* __restrict__ cursor, int* __restrict__ csr_src, int E) {
  int e = blockIdx.x * blockDim.x + threadIdx.x;
  if (e < E) {
    int s = src[e], d = dst[e];
    int pos = atomicAdd(&cursor[d], 1);
    csr_src[pos] = s;
  }
}

// ---------------- f32 GEMM: out = A @ W (+bias), 128 rows x 64 cols per block ----------------

__global__ __launch_bounds__(256) void k_gemm(const float* __restrict__ A, int lda,
                                              const float* __restrict__ W, int ldw,
                                              const float* __restrict__ bias,
                                              float* __restrict__ out, int ldo, int nrows) {
  __shared__ float Ws[64 * 64];     // 16 KB
  __shared__ float xsT[64 * 128];   // 32 KB, k-major
  const int t  = threadIdx.x;
  const int c0 = blockIdx.y * 64;
  const int r0 = blockIdx.x * 128;

  const int rgrp = t & 31;
  const int cgrp = t >> 5;

  float acc[4][8];
#pragma unroll
  for (int i = 0; i < 4; ++i)
#pragma unroll
    for (int j = 0; j < 8; ++j)
      acc[i][j] = bias ? bias[c0 + cgrp * 8 + j] : 0.f;

  const int rr = t & 127;
  const int hk = t >> 7;

  for (int half = 0; half < 2; ++half) {
    const int kbase = half * 64;
    __syncthreads();
    for (int i = t; i < 64 * 16; i += 256) {
      int k  = i >> 4;
      int c4 = (i & 15) << 2;
      *reinterpret_cast<float4*>(&Ws[k * 64 + c4]) =
          *reinterpret_cast<const float4*>(&W[(size_t)(kbase + k) * ldw + c0 + c4]);
    }
    {
      const int row = r0 + rr;
      const float* ap = &A[(size_t)row * lda + kbase + hk * 32];
#pragma unroll
      for (int j = 0; j < 8; ++j) {
        float4 v = make_float4(0.f, 0.f, 0.f, 0.f);
        if (row < nrows) v = *reinterpret_cast<const float4*>(ap + j * 4);
        const int kb = hk * 32 + j * 4;
        xsT[(kb + 0) * 128 + rr] = v.x;
        xsT[(kb + 1) * 128 + rr] = v.y;
        xsT[(kb + 2) * 128 + rr] = v.z;
        xsT[(kb + 3) * 128 + rr] = v.w;
      }
    }
    __syncthreads();
#pragma unroll 4
    for (int k = 0; k < 64; ++k) {
      const float4 xv = *reinterpret_cast<const float4*>(&xsT[k * 128 + rgrp * 4]);
      const float4 w0 = *reinterpret_cast<const float4*>(&Ws[k * 64 + cgrp * 8]);
      const float4 w1 = *reinterpret_cast<const float4*>(&Ws[k * 64 + cgrp * 8 + 4]);
      const float x[4] = {xv.x, xv.y, xv.z, xv.w};
      const float w[8] = {w0.x, w0.y, w0.z, w0.w, w1.x, w1.y, w1.z, w1.w};
#pragma unroll
      for (int i = 0; i < 4; ++i)
#pragma unroll
        for (int j = 0; j < 8; ++j)
          acc[i][j] += x[i] * w[j];
    }
  }

#pragma unroll
  for (int i = 0; i < 4; ++i) {
    const int row = r0 + rgrp * 4 + i;
    if (row < nrows) {
      float* o = &out[(size_t)row * ldo + c0 + cgrp * 8];
      *reinterpret_cast<float4*>(o)     = make_float4(acc[i][0], acc[i][1], acc[i][2], acc[i][3]);
      *reinterpret_cast<float4*>(o + 4) = make_float4(acc[i][4], acc[i][5], acc[i][6], acc[i][7]);
    }
  }
}

// ---------------- aggregation: out[n] = relu( sum_in h[s]*dinv[s]*di + h[n]*di*di + b ) ----
// one 64-lane wave per node; lane holds float4 (32 lanes span the 128-dim row);
// the two wave-halves process two edges per gather instruction (1 KB/instr);
// final __shfl_xor(32) merges halves. coef recomputed from L2-resident dinv.

__global__ __launch_bounds__(256) void k_agg(const float* __restrict__ h,
                                             const int* __restrict__ row_ptr,
                                             const int* __restrict__ csr_src,
                                             const float* __restrict__ dinv,
                                             const float* __restrict__ bias,
                                             float* __restrict__ out, int n) {
  const int node = blockIdx.x * 4 + (threadIdx.x >> 6);
  if (node >= n) return;
  const int lane = threadIdx.x & 63;
  const int sub  = lane >> 5;          // which edge of the pair this half-wave takes
  const int c4   = (lane & 31) << 2;   // feature quad base
  const float di = dinv[node];

  float4 acc = make_float4(0.f, 0.f, 0.f, 0.f);
  const int e0 = row_ptr[node], e1 = row_ptr[node + 1];
  int e = e0;
  for (; e + 8 <= e1; e += 8) {
    const int ia = csr_src[e     + sub];
    const int ib = csr_src[e + 2 + sub];
    const int ic = csr_src[e + 4 + sub];
    const int id = csr_src[e + 6 + sub];
    const float4 va = *reinterpret_cast<const float4*>(&h[(size_t)ia * FD + c4]);
    const float4 vb = *reinterpret_cast<const float4*>(&h[(size_t)ib * FD + c4]);
    const float4 vc = *reinterpret_cast<const float4*>(&h[(size_t)ic * FD + c4]);
    const float4 vd = *reinterpret_cast<const float4*>(&h[(size_t)id * FD + c4]);
    const float ca = dinv[ia] * di;
    const float cb = dinv[ib] * di;
    const float cc = dinv[ic] * di;
    const float cd = dinv[id] * di;
    acc.x += va.x * ca + vb.x * cb + vc.x * cc + vd.x * cd;
    acc.y += va.y * ca + vb.y * cb + vc.y * cc + vd.y * cd;
    acc.z += va.z * ca + vb.z * cb + vc.z * cc + vd.z * cd;
    acc.w += va.w * ca + vb.w * cb + vc.w * cc + vd.w * cd;
  }
  for (; e + 2 <= e1; e += 2) {
    const int i0 = csr_src[e + sub];
    const float4 v = *reinterpret_cast<const float4*>(&h[(size_t)i0 * FD + c4]);
    const float c = dinv[i0] * di;
    acc.x += v.x * c; acc.y += v.y * c; acc.z += v.z * c; acc.w += v.w * c;
  }
  if (e < e1 && sub == 0) {            // odd tail: first half-wave only
    const int i0 = csr_src[e];
    const float4 v = *reinterpret_cast<const float4*>(&h[(size_t)i0 * FD + c4]);
    const float c = dinv[i0] * di;
    acc.x += v.x * c; acc.y += v.y * c; acc.z += v.z * c; acc.w += v.w * c;
  }

  // merge the two half-waves (lane ^ 32 holds the other edge-subset's partial)
  acc.x += __shfl_xor(acc.x, 32);
  acc.y += __shfl_xor(acc.y, 32);
  acc.z += __shfl_xor(acc.z, 32);
  acc.w += __shfl_xor(acc.w, 32);

  const float4 hs = *reinterpret_cast<const float4*>(&h[(size_t)node * FD + c4]);
  const float4 b4 = *reinterpret_cast<const float4*>(&bias[c4]);
  float4 o;
  o.x = fmaxf(acc.x + hs.x * di * di + b4.x, 0.f);
  o.y = fmaxf(acc.y + hs.y * di * di + b4.y, 0.f);
  o.z = fmaxf(acc.z + hs.z * di * di + b4.z, 0.f);
  o.w = fmaxf(acc.w + hs.w * di * di + b4.w, 0.f);
  if (sub == 0)
    *reinterpret_cast<float4*>(&out[(size_t)node * FD + c4]) = o;
}

// ---------------- launch ----------------

extern "C" void kernel_launch(void* const* d_in, const int* in_sizes, int n_in,
                              void* d_out, int out_size, void* d_ws, size_t ws_size,
                              hipStream_t stream) {
  const float* x  = (const float*)d_in[0];
  const float* W1 = (const float*)d_in[1];
  const float* b1 = (const float*)d_in[2];
  const float* W2 = (const float*)d_in[3];
  const float* b2 = (const float*)d_in[4];
  const float* Wf = (const float*)d_in[5];
  const float* bf = (const float*)d_in[6];
  const int*   ei = (const int*)d_in[7];

  const int N = in_sizes[0] / FD;
  const int E = in_sizes[7] / 2;
  const int O = in_sizes[6];
  const int* src = ei;
  const int* dst = ei + E;

  char* ws = (char*)d_ws;
  size_t off = 0;
  auto alloc = [&](size_t bytes) -> void* {
    void* p = ws + off;
    off += (bytes + 255) & ~(size_t)255;
    return p;
  };
  float* A       = (float*)alloc((size_t)N * FD * 4);
  float* B       = (float*)alloc((size_t)N * FD * 4);
  int*   deg     = (int*)  alloc((size_t)N * 4);
  float* dinv    = (float*)alloc((size_t)N * 4);
  int*   row_ptr = (int*)  alloc((size_t)(N + 1) * 4);
  int*   cursor  = (int*)  alloc((size_t)N * 4);
  int*   csr_src = (int*)  alloc((size_t)E * 4);
  int*   part    = (int*)  alloc((size_t)SCAN_B * 4);

  hipMemsetAsync(deg, 0, (size_t)N * 4, stream);
  k_deg     <<<(E + 255) / 256, 256, 0, stream>>>(dst, deg, E);
  k_part    <<<SCAN_B, SCAN_T, 0, stream>>>(deg, dinv, part, N);
  k_scanpart<<<1, SCAN_B, 0, stream>>>(part, row_ptr, N);
  k_rowptr  <<<SCAN_B, SCAN_T, 0, stream>>>(deg, part, row_ptr, cursor, N);
  k_fill    <<<(E + 255) / 256, 256, 0, stream>>>(src, dst, cursor, csr_src, E);

  const int gx = (N + 127) / 128;
  // layer 1: h = x@W1 ; agg+b1+relu
  k_gemm<<<dim3(gx, 2), 256, 0, stream>>>(x, FD, W1, FD, nullptr, A, FD, N);
  k_agg <<<(N + 3) / 4, 256, 0, stream>>>(A, row_ptr, csr_src, dinv, b1, B, N);
  // layer 2
  k_gemm<<<dim3(gx, 2), 256, 0, stream>>>(B, FD, W2, FD, nullptr, A, FD, N);
  k_agg <<<(N + 3) / 4, 256, 0, stream>>>(A, row_ptr, csr_src, dinv, b2, B, N);
  // final linear
  k_gemm<<<dim3(gx, 1), 256, 0, stream>>>(B, FD, Wf, O, bf, (float*)d_out, O, N);
}

// Round 8
// 588.283 us; speedup vs baseline: 1.1514x; 1.1514x over previous
//
#include <hip/hip_runtime.h>

#define FD 128      // feature dim (D == H == 128)
#define SCAN_B 256  // blocks in hierarchical scan
#define SCAN_T 256  // threads per scan block

// ---------------- degree + per-edge rank (atomic return value is free) ----------------

__global__ void k_deg(const int* __restrict__ dst, int* __restrict__ deg,
                      int* __restrict__ rank, int E) {
  int e = blockIdx.x * blockDim.x + threadIdx.x;
  if (e < E) rank[e] = atomicAdd(&deg[dst[e]], 1);
}

// ---------------- hierarchical scan: partials (+ fused dinv) ----------------

__global__ __launch_bounds__(SCAN_T) void k_part(const int* __restrict__ deg,
                                                 float* __restrict__ dinv,
                                                 int* __restrict__ part, int n) {
  const int b = blockIdx.x;
  const int chunk = (n + SCAN_B - 1) / SCAN_B;
  const int lo = b * chunk;
  const int hi = min(lo + chunk, n);
  int sum = 0;
  for (int i = lo + threadIdx.x; i < hi; i += SCAN_T) {
    int d = deg[i];
    sum += d;
    dinv[i] = rsqrtf((float)(d + 1));   // +1 = self-loop
  }
  __shared__ int red[SCAN_T / 64];
  for (int off = 32; off > 0; off >>= 1) sum += __shfl_down(sum, off, 64);
  if ((threadIdx.x & 63) == 0) red[threadIdx.x >> 6] = sum;
  __syncthreads();
  if (threadIdx.x == 0) {
    int s = 0;
#pragma unroll
    for (int w = 0; w < SCAN_T / 64; ++w) s += red[w];
    part[b] = s;
  }
}

__global__ __launch_bounds__(SCAN_B) void k_scanpart(int* __restrict__ part,
                                                     int* __restrict__ row_ptr, int n) {
  __shared__ int s[SCAN_B];
  const int t = threadIdx.x;
  int v = part[t];
  s[t] = v;
  __syncthreads();
  for (int off = 1; off < SCAN_B; off <<= 1) {
    int u = (t >= off) ? s[t - off] : 0;
    __syncthreads();
    s[t] += u;
    __syncthreads();
  }
  part[t] = s[t] - v;                    // exclusive
  if (t == SCAN_B - 1) row_ptr[n] = s[t];
}

__global__ __launch_bounds__(SCAN_T) void k_rowptr(const int* __restrict__ deg,
                                                   const int* __restrict__ part,
                                                   int* __restrict__ row_ptr, int n) {
  const int b = blockIdx.x;
  const int chunk = (n + SCAN_B - 1) / SCAN_B;
  const int lo = b * chunk;
  const int hi = min(lo + chunk, n);
  const int sub = (chunk + SCAN_T - 1) / SCAN_T;
  const int t = threadIdx.x;
  const int slo = min(lo + t * sub, hi);
  const int shi = min(slo + sub, hi);
  int sum = 0;
  for (int i = slo; i < shi; ++i) sum += deg[i];
  __shared__ int s[SCAN_T];
  s[t] = sum;
  __syncthreads();
  for (int off = 1; off < SCAN_T; off <<= 1) {
    int u = (t >= off) ? s[t - off] : 0;
    __syncthreads();
    s[t] += u;
    __syncthreads();
  }
  int run = part[b] + s[t] - sum;
  for (int i = slo; i < shi; ++i) {
    row_ptr[i] = run;
    run += deg[i];
  }
}

// ---------------- CSR fill: atomic-free (pos = row_ptr[dst] + precomputed rank) ----------------

__global__ void k_fill(const int* __restrict__ src, const int* __restrict__ dst,
                       const int* __restrict__ rank, const int* __restrict__ row_ptr,
                       int* __restrict__ csr_src, int E) {
  int e = blockIdx.x * blockDim.x + threadIdx.x;
  if (e < E) {
    csr_src[row_ptr[dst[e]] + rank[e]] = src[e];
  }
}

// ---------------- f32 GEMM: out = A @ W (+bias), 128 rows x 64 cols per block ----------------

__global__ __launch_bounds__(256) void k_gemm(const float* __restrict__ A, int lda,
                                              const float* __restrict__ W, int ldw,
                                              const float* __restrict__ bias,
                                              float* __restrict__ out, int ldo, int nrows) {
  __shared__ float Ws[64 * 64];     // 16 KB
  __shared__ float xsT[64 * 128];   // 32 KB, k-major
  const int t  = threadIdx.x;
  const int c0 = blockIdx.y * 64;
  const int r0 = blockIdx.x * 128;

  const int rgrp = t & 31;
  const int cgrp = t >> 5;

  float acc[4][8];
#pragma unroll
  for (int i = 0; i < 4; ++i)
#pragma unroll
    for (int j = 0; j < 8; ++j)
      acc[i][j] = bias ? bias[c0 + cgrp * 8 + j] : 0.f;

  const int rr = t & 127;
  const int hk = t >> 7;

  for (int half = 0; half < 2; ++half) {
    const int kbase = half * 64;
    __syncthreads();
    for (int i = t; i < 64 * 16; i += 256) {
      int k  = i >> 4;
      int c4 = (i & 15) << 2;
      *reinterpret_cast<float4*>(&Ws[k * 64 + c4]) =
          *reinterpret_cast<const float4*>(&W[(size_t)(kbase + k) * ldw + c0 + c4]);
    }
    {
      const int row = r0 + rr;
      const float* ap = &A[(size_t)row * lda + kbase + hk * 32];
#pragma unroll
      for (int j = 0; j < 8; ++j) {
        float4 v = make_float4(0.f, 0.f, 0.f, 0.f);
        if (row < nrows) v = *reinterpret_cast<const float4*>(ap + j * 4);
        const int kb = hk * 32 + j * 4;
        xsT[(kb + 0) * 128 + rr] = v.x;
        xsT[(kb + 1) * 128 + rr] = v.y;
        xsT[(kb + 2) * 128 + rr] = v.z;
        xsT[(kb + 3) * 128 + rr] = v.w;
      }
    }
    __syncthreads();
#pragma unroll 4
    for (int k = 0; k < 64; ++k) {
      const float4 xv = *reinterpret_cast<const float4*>(&xsT[k * 128 + rgrp * 4]);
      const float4 w0 = *reinterpret_cast<const float4*>(&Ws[k * 64 + cgrp * 8]);
      const float4 w1 = *reinterpret_cast<const float4*>(&Ws[k * 64 + cgrp * 8 + 4]);
      const float x[4] = {xv.x, xv.y, xv.z, xv.w};
      const float w[8] = {w0.x, w0.y, w0.z, w0.w, w1.x, w1.y, w1.z, w1.w};
#pragma unroll
      for (int i = 0; i < 4; ++i)
#pragma unroll
        for (int j = 0; j < 8; ++j)
          acc[i][j] += x[i] * w[j];
    }
  }

#pragma unroll
  for (int i = 0; i < 4; ++i) {
    const int row = r0 + rgrp * 4 + i;
    if (row < nrows) {
      float* o = &out[(size_t)row * ldo + c0 + cgrp * 8];
      *reinterpret_cast<float4*>(o)     = make_float4(acc[i][0], acc[i][1], acc[i][2], acc[i][3]);
      *reinterpret_cast<float4*>(o + 4) = make_float4(acc[i][4], acc[i][5], acc[i][6], acc[i][7]);
    }
  }
}

// ---------------- aggregation: out[n] = relu( sum_in h[s]*dinv[s]*di + h[n]*di*di + b ) ----
// one 64-lane wave per node; lane holds float4 (32 lanes span the 128-dim row);
// the two wave-halves process two edges per gather instruction (1 KB/instr);
// final __shfl_xor(32) merges halves. coef recomputed from L2-resident dinv.

__global__ __launch_bounds__(256) void k_agg(const float* __restrict__ h,
                                             const int* __restrict__ row_ptr,
                                             const int* __restrict__ csr_src,
                                             const float* __restrict__ dinv,
                                             const float* __restrict__ bias,
                                             float* __restrict__ out, int n) {
  const int node = blockIdx.x * 4 + (threadIdx.x >> 6);
  if (node >= n) return;
  const int lane = threadIdx.x & 63;
  const int sub  = lane >> 5;          // which edge of the pair this half-wave takes
  const int c4   = (lane & 31) << 2;   // feature quad base
  const float di = dinv[node];

  float4 acc = make_float4(0.f, 0.f, 0.f, 0.f);
  const int e0 = row_ptr[node], e1 = row_ptr[node + 1];
  int e = e0;
  for (; e + 8 <= e1; e += 8) {
    const int ia = csr_src[e     + sub];
    const int ib = csr_src[e + 2 + sub];
    const int ic = csr_src[e + 4 + sub];
    const int id = csr_src[e + 6 + sub];
    const float4 va = *reinterpret_cast<const float4*>(&h[(size_t)ia * FD + c4]);
    const float4 vb = *reinterpret_cast<const float4*>(&h[(size_t)ib * FD + c4]);
    const float4 vc = *reinterpret_cast<const float4*>(&h[(size_t)ic * FD + c4]);
    const float4 vd = *reinterpret_cast<const float4*>(&h[(size_t)id * FD + c4]);
    const float ca = dinv[ia] * di;
    const float cb = dinv[ib] * di;
    const float cc = dinv[ic] * di;
    const float cd = dinv[id] * di;
    acc.x += va.x * ca + vb.x * cb + vc.x * cc + vd.x * cd;
    acc.y += va.y * ca + vb.y * cb + vc.y * cc + vd.y * cd;
    acc.z += va.z * ca + vb.z * cb + vc.z * cc + vd.z * cd;
    acc.w += va.w * ca + vb.w * cb + vc.w * cc + vd.w * cd;
  }
  for (; e + 2 <= e1; e += 2) {
    const int i0 = csr_src[e + sub];
    const float4 v = *reinterpret_cast<const float4*>(&h[(size_t)i0 * FD + c4]);
    const float c = dinv[i0] * di;
    acc.x += v.x * c; acc.y += v.y * c; acc.z += v.z * c; acc.w += v.w * c;
  }
  if (e < e1 && sub == 0) {            // odd tail: first half-wave only
    const int i0 = csr_src[e];
    const float4 v = *reinterpret_cast<const float4*>(&h[(size_t)i0 * FD + c4]);
    const float c = dinv[i0] * di;
    acc.x += v.x * c; acc.y += v.y * c; acc.z += v.z * c; acc.w += v.w * c;
  }

  // merge the two half-waves (lane ^ 32 holds the other edge-subset's partial)
  acc.x += __shfl_xor(acc.x, 32);
  acc.y += __shfl_xor(acc.y, 32);
  acc.z += __shfl_xor(acc.z, 32);
  acc.w += __shfl_xor(acc.w, 32);

  const float4 hs = *reinterpret_cast<const float4*>(&h[(size_t)node * FD + c4]);
  const float4 b4 = *reinterpret_cast<const float4*>(&bias[c4]);
  float4 o;
  o.x = fmaxf(acc.x + hs.x * di * di + b4.x, 0.f);
  o.y = fmaxf(acc.y + hs.y * di * di + b4.y, 0.f);
  o.z = fmaxf(acc.z + hs.z * di * di + b4.z, 0.f);
  o.w = fmaxf(acc.w + hs.w * di * di + b4.w, 0.f);
  if (sub == 0)
    *reinterpret_cast<float4*>(&out[(size_t)node * FD + c4]) = o;
}

// ---------------- launch ----------------

extern "C" void kernel_launch(void* const* d_in, const int* in_sizes, int n_in,
                              void* d_out, int out_size, void* d_ws, size_t ws_size,
                              hipStream_t stream) {
  const float* x  = (const float*)d_in[0];
  const float* W1 = (const float*)d_in[1];
  const float* b1 = (const float*)d_in[2];
  const float* W2 = (const float*)d_in[3];
  const float* b2 = (const float*)d_in[4];
  const float* Wf = (const float*)d_in[5];
  const float* bf = (const float*)d_in[6];
  const int*   ei = (const int*)d_in[7];

  const int N = in_sizes[0] / FD;
  const int E = in_sizes[7] / 2;
  const int O = in_sizes[6];
  const int* src = ei;
  const int* dst = ei + E;

  char* ws = (char*)d_ws;
  size_t off = 0;
  auto alloc = [&](size_t bytes) -> void* {
    void* p = ws + off;
    off += (bytes + 255) & ~(size_t)255;
    return p;
  };
  float* A       = (float*)alloc((size_t)N * FD * 4);
  float* B       = (float*)alloc((size_t)N * FD * 4);
  int*   deg     = (int*)  alloc((size_t)N * 4);
  float* dinv    = (float*)alloc((size_t)N * 4);
  int*   row_ptr = (int*)  alloc((size_t)(N + 1) * 4);
  int*   rank    = (int*)  alloc((size_t)E * 4);
  int*   csr_src = (int*)  alloc((size_t)E * 4);
  int*   part    = (int*)  alloc((size_t)SCAN_B * 4);

  hipMemsetAsync(deg, 0, (size_t)N * 4, stream);
  k_deg     <<<(E + 255) / 256, 256, 0, stream>>>(dst, deg, rank, E);
  k_part    <<<SCAN_B, SCAN_T, 0, stream>>>(deg, dinv, part, N);
  k_scanpart<<<1, SCAN_B, 0, stream>>>(part, row_ptr, N);
  k_rowptr  <<<SCAN_B, SCAN_T, 0, stream>>>(deg, part, row_ptr, N);
  k_fill    <<<(E + 255) / 256, 256, 0, stream>>>(src, dst, rank, row_ptr, csr_src, E);

  const int gx = (N + 127) / 128;
  // layer 1: h = x@W1 ; agg+b1+relu
  k_gemm<<<dim3(gx, 2), 256, 0, stream>>>(x, FD, W1, FD, nullptr, A, FD, N);
  k_agg <<<(N + 3) / 4, 256, 0, stream>>>(A, row_ptr, csr_src, dinv, b1, B, N);
  // layer 2
  k_gemm<<<dim3(gx, 2), 256, 0, stream>>>(B, FD, W2, FD, nullptr, A, FD, N);
  k_agg <<<(N + 3) / 4, 256, 0, stream>>>(A, row_ptr, csr_src, dinv, b2, B, N);
  // final linear
  k_gemm<<<dim3(gx, 1), 256, 0, stream>>>(B, FD, Wf, O, bf, (float*)d_out, O, N);
}